// Round 2
// 81.160 us; speedup vs baseline: 1.0870x; 1.0870x over previous
//
#include <hip/hip_runtime.h>

// Performer causal linear attention (generalized relu kernel), fp32 in/out.
// B=1, H=8, N=1024, D=64, M=128. Chunked formulation, chunk C=128:
//   qp = relu(norm * q @ proj^T) + eps ; kp likewise
//   Z  = cumsum_n kp ; W = qp / Z
//   out_c = W_c @ S0_c + tril(W_c @ Kp_c^T) @ V_c ; S0_c = prefix of Kp^T V
// R14 = R13 resubmitted (round 1 was an infra failure, no signal).
// R13: add k_prefix kernel computing chunk-prefix S0pre[h][c][M][D] (bf16) and
// exclusive z-scan zpre[h][s][M] (fp32) ONCE, instead of every k_attn block
// redundantly re-summing c*4 G-rows (448KB + ~1.5us VALU on heavy blocks,
// identical across all 4 subs) and re-scanning kpart. Accumulation order and
// rounding bit-identical to R12. k_attn prefetches S0 (16KB) + zinit at start.
static constexpr int H = 8, N = 1024, D = 64, M = 128, CHUNK = 128, NC = 8;
static constexpr float EPS = 1e-3f;
static constexpr float NORM = 0.35355339059327373f; // 64^-0.25

typedef __attribute__((ext_vector_type(8))) short short8;
typedef __attribute__((ext_vector_type(4))) float f32x4;

__device__ inline unsigned short f2bf(float x) {
    unsigned u = __float_as_uint(x);
    return (unsigned short)((u + 0x7fffu + ((u >> 16) & 1u)) >> 16);
}
__device__ inline float bf2f(unsigned short u) {
    return __uint_as_float(((unsigned)u) << 16);
}
__device__ inline ushort4 pack4(float4 g) {
    return (ushort4){f2bf(g.x), f2bf(g.y), f2bf(g.z), f2bf(g.w)};
}

// -------- K1: qpb/kpb = bf16(relu(norm x @ proj^T)+eps), Gpb, kpart.
// grid (32 rblk, 8 h), 512 thr. One block: 32 rows of BOTH q and k.
// (identical to R12)
__global__ __launch_bounds__(512) void k_projg(const float* __restrict__ q,
                                               const float* __restrict__ k,
                                               const float* __restrict__ proj,
                                               const float* __restrict__ v,
                                               unsigned short* __restrict__ qpb,
                                               unsigned short* __restrict__ kpb,
                                               unsigned short* __restrict__ Gpb,
                                               float* __restrict__ kpart) {
    __shared__ __align__(16) short smem[30208]; // 60.4 KB
    short* projb = smem;         // [m 128][72] B-operand
    short* xb = smem + 9216;     // [r 64][72] A-operand (q rows 0-31, k 32-63)
    short* obuf = smem + 13824;  // [64][136] out tile / later [128][68] G
    short* kpT = smem + 22528;   // [m 128][40] A-operand for G
    short* vT = smem + 27648;    // [e 64][40] B-operand for G
    const int tid = threadIdx.x;
    const int rblk = blockIdx.x;
    const int h = blockIdx.y;
    const int rowbase = h * N + rblk * 32;
    const int lane = tid & 63, wv = tid >> 6;
    const int rt = wv & 3, mh = wv >> 2;
    const int fr = lane & 15, fq = lane >> 4;

    for (int i4 = tid; i4 < 2048; i4 += 512) {
        int m = i4 >> 4, dq = i4 & 15;
        *(ushort4*)&projb[m * 72 + dq * 4] = pack4(*(const float4*)&proj[i4 * 4]);
    }
    {
        int r = tid >> 4, dq = tid & 15;
        float4 g = *(const float4*)&q[(rowbase + r) * D + dq * 4];
        g.x *= NORM; g.y *= NORM; g.z *= NORM; g.w *= NORM;
        *(ushort4*)&xb[r * 72 + dq * 4] = pack4(g);
        float4 gk = *(const float4*)&k[(rowbase + r) * D + dq * 4];
        gk.x *= NORM; gk.y *= NORM; gk.z *= NORM; gk.w *= NORM;
        *(ushort4*)&xb[(32 + r) * 72 + dq * 4] = pack4(gk);
        int rv = tid & 31, e4 = (tid >> 5) * 4;
        float4 gv = *(const float4*)&v[(rowbase + rv) * D + e4];
        vT[(e4 + 0) * 40 + rv] = (short)f2bf(gv.x);
        vT[(e4 + 1) * 40 + rv] = (short)f2bf(gv.y);
        vT[(e4 + 2) * 40 + rv] = (short)f2bf(gv.z);
        vT[(e4 + 3) * 40 + rv] = (short)f2bf(gv.w);
    }
    __syncthreads();

    f32x4 accp[4];
#pragma unroll
    for (int i = 0; i < 4; i++) accp[i] = (f32x4){0.f, 0.f, 0.f, 0.f};
#pragma unroll
    for (int kt = 0; kt < 2; kt++) {
        short8 a = *(const short8*)&xb[(16 * rt + fr) * 72 + kt * 32 + fq * 8];
#pragma unroll
        for (int i = 0; i < 4; i++) {
            const int mt = mh * 4 + i;
            short8 bb = *(const short8*)&projb[(16 * mt + fr) * 72 + kt * 32 + fq * 8];
            accp[i] = __builtin_amdgcn_mfma_f32_16x16x32_bf16(a, bb, accp[i], 0, 0, 0);
        }
    }
#pragma unroll
    for (int i = 0; i < 4; i++) {
        const int mt = mh * 4 + i;
#pragma unroll
        for (int reg = 0; reg < 4; reg++) {
            const int r = 16 * rt + fq * 4 + reg;
            const int m = 16 * mt + fr;
            unsigned short bv = f2bf(fmaxf(accp[i][reg], 0.f) + EPS);
            obuf[r * 136 + m] = (short)bv;
            if (rt >= 2) kpT[m * 40 + (r - 32)] = (short)bv;
        }
    }
    __syncthreads();

    for (int i = tid; i < 2048; i += 512) {
        int r = i >> 5, cu = i & 31;
        ushort4 val = *(const ushort4*)&obuf[r * 136 + cu * 4];
        unsigned short* g = (r < 32) ? &qpb[(rowbase + r) * M + cu * 4]
                                     : &kpb[(rowbase + r - 32) * M + cu * 4];
        *(ushort4*)g = val;
    }
    const int gb = h * 32 + rblk;
    if (tid < 128) {
        float ks = 0.f;
#pragma unroll 8
        for (int r = 0; r < 32; r++) ks += bf2f((unsigned short)kpT[tid * 40 + r]);
        kpart[gb * M + tid] = ks;
    }
    __syncthreads();

    f32x4 gacc[4];
#pragma unroll
    for (int et = 0; et < 4; et++) gacc[et] = (f32x4){0.f, 0.f, 0.f, 0.f};
    {
        short8 a = *(const short8*)&kpT[(16 * wv + fr) * 40 + fq * 8];
#pragma unroll
        for (int et = 0; et < 4; et++) {
            short8 bb = *(const short8*)&vT[(16 * et + fr) * 40 + fq * 8];
            gacc[et] = __builtin_amdgcn_mfma_f32_16x16x32_bf16(a, bb, gacc[et], 0, 0, 0);
        }
    }
#pragma unroll
    for (int et = 0; et < 4; et++)
#pragma unroll
        for (int reg = 0; reg < 4; reg++) {
            const int m = 16 * wv + fq * 4 + reg;
            obuf[m * 68 + 16 * et + fr] = (short)f2bf(gacc[et][reg]);
        }
    __syncthreads();
    for (int i = tid; i < 2048; i += 512) {
        int m = i >> 4, e4 = (i & 15) * 4;
        *(ushort4*)&Gpb[(gb * M + m) * D + e4] = *(const ushort4*)&obuf[m * 68 + e4];
    }
}

// -------- K1.5 (R13): chunk-prefix of G and exclusive scan of kpart, ONCE.
// grid (8 h * 8 oct), 256 thr. Each block owns 1024 elems of [M*D=8192].
// S0pre[h][c] = sum over s < 4c of G[h][s]; fp32 accum in s-order, one f2bf
// per chunk boundary — bit-identical to R12's per-block s0r accumulation.
__global__ __launch_bounds__(256) void k_prefix(const float* __restrict__ kpart,
                                                const unsigned short* __restrict__ Gpb,
                                                float* __restrict__ zpre,
                                                unsigned short* __restrict__ S0pre) {
    const int h = blockIdx.x >> 3, oct = blockIdx.x & 7;
    const int tid = threadIdx.x;
    const int eb = oct * 1024 + tid * 4;
    float a0 = 0.f, a1 = 0.f, a2 = 0.f, a3 = 0.f;
#pragma unroll
    for (int c = 0; c < 8; c++) {
        ushort4 w = {f2bf(a0), f2bf(a1), f2bf(a2), f2bf(a3)};
        *(ushort4*)&S0pre[(h * 8 + c) * (M * D) + eb] = w;
#pragma unroll
        for (int p = 0; p < 4; p++) {
            ushort4 g = *(const ushort4*)&Gpb[(h * 32 + c * 4 + p) * (M * D) + eb];
            a0 += bf2f(g.x);
            a1 += bf2f(g.y);
            a2 += bf2f(g.z);
            a3 += bf2f(g.w);
        }
    }
    // exclusive prefix of kpart over s (same fp32 order as R12's z-scan)
    if (oct == 0 && tid < 128) {
        float vals[32];
#pragma unroll
        for (int s = 0; s < 32; s++) vals[s] = kpart[(h * 32 + s) * M + tid];
        float z = 0.f;
#pragma unroll
        for (int s = 0; s < 32; s++) {
            zpre[(h * 32 + s) * M + tid] = z;
            z += vals[s];
        }
    }
}

// -------- K2: grid (64, 4 subs), 512 thr. Per block: 32 output rows x 64 e.
// R13: S0 and z-prefix read precomputed (prefetched at kernel start);
// removes the per-block c*4-row G accumulation loop and the kpart scan.
__global__ __launch_bounds__(512) void k_attn(const unsigned short* __restrict__ qpb,
                                              const unsigned short* __restrict__ kpb,
                                              const float* __restrict__ zpre,
                                              const unsigned short* __restrict__ S0pre,
                                              const float* __restrict__ v,
                                              float* __restrict__ out) {
    __shared__ __align__(16) short smem[26112]; // 52.2 KB
    short* bufA = smem;         // W [32][136]
    short* bufB = smem + 4352;  // Kp [<=128][136]; post-P1: S0T[64][136] + VT[64][136]
    short* bufC = smem + 21760; // qp [32][136] then Pb [32][136]
    short* s0t = bufB;
    short* vT = bufB + 8704;
    const int tid = threadIdx.x;
    const int b = blockIdx.x;
    const int sub = blockIdx.y;
    const int h = b >> 3, c = 7 - (b & 7); // heavy chunks first
    const int chunkbase = h * N + c * CHUNK;
    const int rowstart = chunkbase + sub * 32;
    const int jrows = (sub + 1) * 32; // causal row count
    const int lane = tid & 63, wv = tid >> 6;
    const int rt = wv & 1, js = wv >> 1;
    const int fr = lane & 15, fq = lane >> 4;

    // ---- prefetch V rows (full chunk, 4 float4/thread) into regs
    float4 vpre[4];
#pragma unroll
    for (int t = 0; t < 4; t++) {
        const int i = tid + t * 512;
        const int j = i >> 4, e4 = (i & 15) * 4;
        vpre[t] = *(const float4*)&v[(chunkbase + j) * D + e4];
    }
    // ---- prefetch this chunk's S0 row segment (16 bf16/thread, coalesced)
    const int pm = tid >> 2, peb = (tid & 3) * 16;
    short8 s0a = *(const short8*)&S0pre[(h * 8 + c) * (M * D) + pm * D + peb];
    short8 s0b = *(const short8*)&S0pre[(h * 8 + c) * (M * D) + pm * D + peb + 8];
    // ---- prefetch z prefix for this (c, sub)
    float zinit = 0.f;
    if (tid < 128) zinit = zpre[(h * 32 + c * 4 + sub) * M + tid];

    // ---- stage Kp causal rows + own qp rows (coalesced uint loads)
    {
        const unsigned int* src = (const unsigned int*)kpb;
        for (int i = tid; i < jrows * 64; i += 512) {
            int j = i >> 6, mu = i & 63;
            ((unsigned int*)&bufB[j * 136])[mu] = src[(chunkbase + j) * 64 + mu];
        }
        const unsigned int* srcq = (const unsigned int*)qpb;
        for (int i = tid; i < 2048; i += 512) {
            int r = i >> 6, mu = i & 63;
            ((unsigned int*)&bufC[r * 136])[mu] = srcq[(rowstart + r) * 64 + mu];
        }
    }
    __syncthreads(); // (1)

    // ---- in-chunk z-scan (tid<128, LDS-sourced), seeded from zpre
    if (tid < 128) {
        const int m = tid;
        float z = zinit;
#pragma unroll 8
        for (int r = 0; r < 32; r++) {
            z += bf2f((unsigned short)bufB[(sub * 32 + r) * 136 + m]);
            bufA[r * 136 + m] = (short)f2bf(
                bf2f((unsigned short)bufC[r * 136 + m]) * __builtin_amdgcn_rcpf(z));
        }
    }
    __syncthreads(); // (2) W ready; qp consumed

    // ---- P1: A = tril(W @ Kp^T). Wave (rt, js): jt = 2*js + jl.
    const int jtmax = 2 * sub + 2;
    f32x4 acc1[2];
    acc1[0] = (f32x4){0.f, 0.f, 0.f, 0.f};
    acc1[1] = (f32x4){0.f, 0.f, 0.f, 0.f};
#pragma unroll
    for (int kt = 0; kt < 4; kt++) {
        short8 a = *(const short8*)&bufA[(16 * rt + fr) * 136 + kt * 32 + fq * 8];
#pragma unroll
        for (int jl = 0; jl < 2; jl++) {
            const int jt = 2 * js + jl;
            if (jt < jtmax) {
                short8 bb =
                    *(const short8*)&bufB[(16 * jt + fr) * 136 + kt * 32 + fq * 8];
                acc1[jl] =
                    __builtin_amdgcn_mfma_f32_16x16x32_bf16(a, bb, acc1[jl], 0, 0, 0);
            }
        }
    }
    __syncthreads(); // (3) Kp reads done -> bufB reusable; bufC free

    // ---- Pb (masked) -> bufC ; S0T from prefetched regs ; VT from regs
#pragma unroll
    for (int jl = 0; jl < 2; jl++) {
        const int jt = 2 * js + jl;
        if (jt < jtmax) {
            const int j = 16 * jt + fr;
#pragma unroll
            for (int reg = 0; reg < 4; reg++) {
                const int nloc = 16 * rt + fq * 4 + reg;
                float val = (j <= sub * 32 + nloc) ? acc1[jl][reg] : 0.f;
                bufC[nloc * 136 + j] = (short)f2bf(val);
            }
        }
    }
    {
#pragma unroll
        for (int j = 0; j < 8; j++) {
            s0t[(peb + j) * 136 + pm] = s0a[j];
            s0t[(peb + 8 + j) * 136 + pm] = s0b[j];
        }
    }
#pragma unroll
    for (int t = 0; t < 4; t++) {
        const int i = tid + t * 512;
        const int j = i >> 4, e4 = (i & 15) * 4;
        vT[(e4 + 0) * 136 + j] = (short)f2bf(vpre[t].x);
        vT[(e4 + 1) * 136 + j] = (short)f2bf(vpre[t].y);
        vT[(e4 + 2) * 136 + j] = (short)f2bf(vpre[t].z);
        vT[(e4 + 3) * 136 + j] = (short)f2bf(vpre[t].w);
    }
    __syncthreads(); // (4)

    // ---- P2a: out = W @ S0 (K=128); wave (rt, et=js)
    f32x4 acc2 = (f32x4){0.f, 0.f, 0.f, 0.f};
#pragma unroll
    for (int kt = 0; kt < 4; kt++) {
        short8 a = *(const short8*)&bufA[(16 * rt + fr) * 136 + kt * 32 + fq * 8];
        short8 bb = *(const short8*)&s0t[(16 * js + fr) * 136 + kt * 32 + fq * 8];
        acc2 = __builtin_amdgcn_mfma_f32_16x16x32_bf16(a, bb, acc2, 0, 0, 0);
    }
    // ---- P2b: out += P @ V (K limited to (sub+1)*32 by causality)
    const int ktmax = sub + 1;
    for (int kt = 0; kt < ktmax; kt++) {
        short8 a = *(const short8*)&bufC[(16 * rt + fr) * 136 + kt * 32 + fq * 8];
        short8 bb = *(const short8*)&vT[(16 * js + fr) * 136 + kt * 32 + fq * 8];
        acc2 = __builtin_amdgcn_mfma_f32_16x16x32_bf16(a, bb, acc2, 0, 0, 0);
    }

    // ---- epilogue
#pragma unroll
    for (int reg = 0; reg < 4; reg++) {
        out[(rowstart + 16 * rt + fq * 4 + reg) * D + 16 * js + fr] = acc2[reg];
    }
}

extern "C" void kernel_launch(void* const* d_in, const int* in_sizes, int n_in,
                              void* d_out, int out_size, void* d_ws, size_t ws_size,
                              hipStream_t stream) {
    const float* q = (const float*)d_in[0];
    const float* k = (const float*)d_in[1];
    const float* v = (const float*)d_in[2];
    const float* proj = (const float*)d_in[3];
    float* out = (float*)d_out;

    // workspace: kpart 128KB fp32; qpb/kpb 2MB bf16; Gpb 4MB bf16;
    // zpre 128KB fp32; S0pre 1MB bf16
    float* ws = (float*)d_ws;
    float* kpart = ws;                                           // H*32*M
    unsigned short* qpb = (unsigned short*)(kpart + H * 32 * M); // H*N*M
    unsigned short* kpb = qpb + H * N * M;                       // H*N*M
    unsigned short* Gpb = kpb + H * N * M;                       // H*32*M*D
    float* zpre = (float*)(Gpb + H * 32 * M * D);                // H*32*M
    unsigned short* S0pre = (unsigned short*)(zpre + H * 32 * M); // H*8*M*D

    k_projg<<<dim3(32, H), 512, 0, stream>>>(q, k, proj, v, qpb, kpb, Gpb,
                                             kpart);
    k_prefix<<<dim3(64), 256, 0, stream>>>(kpart, Gpb, zpre, S0pre);
    k_attn<<<dim3(H * NC, 4), 512, 0, stream>>>(qpb, kpb, zpre, S0pre, v, out);
}

// Round 3
// 80.302 us; speedup vs baseline: 1.0986x; 1.0107x over previous
//
#include <hip/hip_runtime.h>

// Performer causal linear attention (generalized relu kernel), fp32 in/out.
// B=1, H=8, N=1024, D=64, M=128. Sub-block formulation, S=32 rows/block:
//   qp = relu(norm * q @ proj^T) + eps ; kp likewise
//   Z  = cumsum_n kp ; W = qp / Z
//   out_s = W_s @ S0_s + tril(W_s @ Kp_s^T) @ V_s ; S0_s = prefix of Kp^T V
// R15: S0 prefix pushed to s-granularity (32 rows) so ALL 256 k_attn blocks
// are identical (R13's grid (64,4) was tail-bound by sub=3 blocks staging
// 32KB Kp + 2x the MFMA of sub=0). Every block now stages only its own 32
// rows of Kp/qp/V plus one 16KB S0 slab; P1 is a 32x32 tril; P2b has K=32.
// fp32 prefix accumulation order in k_prefix unchanged (bit-identical chain,
// more write points). zpre was already s-granular.
static constexpr int H = 8, N = 1024, D = 64, M = 128;
static constexpr float EPS = 1e-3f;
static constexpr float NORM = 0.35355339059327373f; // 64^-0.25

typedef __attribute__((ext_vector_type(8))) short short8;
typedef __attribute__((ext_vector_type(4))) float f32x4;

__device__ inline unsigned short f2bf(float x) {
    unsigned u = __float_as_uint(x);
    return (unsigned short)((u + 0x7fffu + ((u >> 16) & 1u)) >> 16);
}
__device__ inline float bf2f(unsigned short u) {
    return __uint_as_float(((unsigned)u) << 16);
}
__device__ inline ushort4 pack4(float4 g) {
    return (ushort4){f2bf(g.x), f2bf(g.y), f2bf(g.z), f2bf(g.w)};
}

// -------- K1: qpb/kpb = bf16(relu(norm x @ proj^T)+eps), Gpb, kpart.
// grid (32 rblk, 8 h), 512 thr. One block: 32 rows of BOTH q and k.
// (identical to R12/R13)
__global__ __launch_bounds__(512) void k_projg(const float* __restrict__ q,
                                               const float* __restrict__ k,
                                               const float* __restrict__ proj,
                                               const float* __restrict__ v,
                                               unsigned short* __restrict__ qpb,
                                               unsigned short* __restrict__ kpb,
                                               unsigned short* __restrict__ Gpb,
                                               float* __restrict__ kpart) {
    __shared__ __align__(16) short smem[30208]; // 60.4 KB
    short* projb = smem;         // [m 128][72] B-operand
    short* xb = smem + 9216;     // [r 64][72] A-operand (q rows 0-31, k 32-63)
    short* obuf = smem + 13824;  // [64][136] out tile / later [128][68] G
    short* kpT = smem + 22528;   // [m 128][40] A-operand for G
    short* vT = smem + 27648;    // [e 64][40] B-operand for G
    const int tid = threadIdx.x;
    const int rblk = blockIdx.x;
    const int h = blockIdx.y;
    const int rowbase = h * N + rblk * 32;
    const int lane = tid & 63, wv = tid >> 6;
    const int rt = wv & 3, mh = wv >> 2;
    const int fr = lane & 15, fq = lane >> 4;

    for (int i4 = tid; i4 < 2048; i4 += 512) {
        int m = i4 >> 4, dq = i4 & 15;
        *(ushort4*)&projb[m * 72 + dq * 4] = pack4(*(const float4*)&proj[i4 * 4]);
    }
    {
        int r = tid >> 4, dq = tid & 15;
        float4 g = *(const float4*)&q[(rowbase + r) * D + dq * 4];
        g.x *= NORM; g.y *= NORM; g.z *= NORM; g.w *= NORM;
        *(ushort4*)&xb[r * 72 + dq * 4] = pack4(g);
        float4 gk = *(const float4*)&k[(rowbase + r) * D + dq * 4];
        gk.x *= NORM; gk.y *= NORM; gk.z *= NORM; gk.w *= NORM;
        *(ushort4*)&xb[(32 + r) * 72 + dq * 4] = pack4(gk);
        int rv = tid & 31, e4 = (tid >> 5) * 4;
        float4 gv = *(const float4*)&v[(rowbase + rv) * D + e4];
        vT[(e4 + 0) * 40 + rv] = (short)f2bf(gv.x);
        vT[(e4 + 1) * 40 + rv] = (short)f2bf(gv.y);
        vT[(e4 + 2) * 40 + rv] = (short)f2bf(gv.z);
        vT[(e4 + 3) * 40 + rv] = (short)f2bf(gv.w);
    }
    __syncthreads();

    f32x4 accp[4];
#pragma unroll
    for (int i = 0; i < 4; i++) accp[i] = (f32x4){0.f, 0.f, 0.f, 0.f};
#pragma unroll
    for (int kt = 0; kt < 2; kt++) {
        short8 a = *(const short8*)&xb[(16 * rt + fr) * 72 + kt * 32 + fq * 8];
#pragma unroll
        for (int i = 0; i < 4; i++) {
            const int mt = mh * 4 + i;
            short8 bb = *(const short8*)&projb[(16 * mt + fr) * 72 + kt * 32 + fq * 8];
            accp[i] = __builtin_amdgcn_mfma_f32_16x16x32_bf16(a, bb, accp[i], 0, 0, 0);
        }
    }
#pragma unroll
    for (int i = 0; i < 4; i++) {
        const int mt = mh * 4 + i;
#pragma unroll
        for (int reg = 0; reg < 4; reg++) {
            const int r = 16 * rt + fq * 4 + reg;
            const int m = 16 * mt + fr;
            unsigned short bv = f2bf(fmaxf(accp[i][reg], 0.f) + EPS);
            obuf[r * 136 + m] = (short)bv;
            if (rt >= 2) kpT[m * 40 + (r - 32)] = (short)bv;
        }
    }
    __syncthreads();

    for (int i = tid; i < 2048; i += 512) {
        int r = i >> 5, cu = i & 31;
        ushort4 val = *(const ushort4*)&obuf[r * 136 + cu * 4];
        unsigned short* g = (r < 32) ? &qpb[(rowbase + r) * M + cu * 4]
                                     : &kpb[(rowbase + r - 32) * M + cu * 4];
        *(ushort4*)g = val;
    }
    const int gb = h * 32 + rblk;
    if (tid < 128) {
        float ks = 0.f;
#pragma unroll 8
        for (int r = 0; r < 32; r++) ks += bf2f((unsigned short)kpT[tid * 40 + r]);
        kpart[gb * M + tid] = ks;
    }
    __syncthreads();

    f32x4 gacc[4];
#pragma unroll
    for (int et = 0; et < 4; et++) gacc[et] = (f32x4){0.f, 0.f, 0.f, 0.f};
    {
        short8 a = *(const short8*)&kpT[(16 * wv + fr) * 40 + fq * 8];
#pragma unroll
        for (int et = 0; et < 4; et++) {
            short8 bb = *(const short8*)&vT[(16 * et + fr) * 40 + fq * 8];
            gacc[et] = __builtin_amdgcn_mfma_f32_16x16x32_bf16(a, bb, gacc[et], 0, 0, 0);
        }
    }
#pragma unroll
    for (int et = 0; et < 4; et++)
#pragma unroll
        for (int reg = 0; reg < 4; reg++) {
            const int m = 16 * wv + fq * 4 + reg;
            obuf[m * 68 + 16 * et + fr] = (short)f2bf(gacc[et][reg]);
        }
    __syncthreads();
    for (int i = tid; i < 2048; i += 512) {
        int m = i >> 4, e4 = (i & 15) * 4;
        *(ushort4*)&Gpb[(gb * M + m) * D + e4] = *(const ushort4*)&obuf[m * 68 + e4];
    }
}

// -------- K1.5: s-granular prefix of G and exclusive scan of kpart, ONCE.
// grid (8 h * 8 oct), 256 thr. Each block owns 1024 elems of [M*D=8192].
// S0pre[h][s] = sum over s' < s of G[h][s']; fp32 accum in s-order —
// bit-identical chain to R13, written at every s boundary (R15).
__global__ __launch_bounds__(256) void k_prefix(const float* __restrict__ kpart,
                                                const unsigned short* __restrict__ Gpb,
                                                float* __restrict__ zpre,
                                                unsigned short* __restrict__ S0pre) {
    const int h = blockIdx.x >> 3, oct = blockIdx.x & 7;
    const int tid = threadIdx.x;
    const int eb = oct * 1024 + tid * 4;
    float a0 = 0.f, a1 = 0.f, a2 = 0.f, a3 = 0.f;
#pragma unroll 4
    for (int s = 0; s < 32; s++) {
        ushort4 w = {f2bf(a0), f2bf(a1), f2bf(a2), f2bf(a3)};
        *(ushort4*)&S0pre[(h * 32 + s) * (M * D) + eb] = w;
        ushort4 g = *(const ushort4*)&Gpb[(h * 32 + s) * (M * D) + eb];
        a0 += bf2f(g.x);
        a1 += bf2f(g.y);
        a2 += bf2f(g.z);
        a3 += bf2f(g.w);
    }
    // exclusive prefix of kpart over s (same fp32 order as before)
    if (oct == 0 && tid < 128) {
        float vals[32];
#pragma unroll
        for (int s = 0; s < 32; s++) vals[s] = kpart[(h * 32 + s) * M + tid];
        float z = 0.f;
#pragma unroll
        for (int s = 0; s < 32; s++) {
            zpre[(h * 32 + s) * M + tid] = z;
            z += vals[s];
        }
    }
}

// -------- K2 (R15): grid (256), 512 thr. Every block identical:
// 32 output rows. out = W @ S0pre[s] + tril(W @ Kp_own^T) @ V_own.
__global__ __launch_bounds__(512) void k_attn(const unsigned short* __restrict__ qpb,
                                              const unsigned short* __restrict__ kpb,
                                              const float* __restrict__ zpre,
                                              const unsigned short* __restrict__ S0pre,
                                              const float* __restrict__ v,
                                              float* __restrict__ out) {
    __shared__ __align__(16) short smem[25600]; // 51.2 KB
    short* bufW = smem;          // W  [32 n][136]
    short* bufK = smem + 4352;   // Kp [32 j][136]
    short* bufQ = smem + 8704;   // qp [32 n][136]
    short* s0t  = smem + 13056;  // S0^T [64 e][136] (m in columns)
    short* vT   = smem + 21760;  // V^T  [64 e][40]  (j in columns)
    short* bufP = smem + 24320;  // Pb   [32 n][40]  (j in columns)
    const int tid = threadIdx.x;
    const int b = blockIdx.x;
    const int h = b >> 5, s = b & 31;
    const int rowstart = h * N + s * 32;
    const int lane = tid & 63, wv = tid >> 6;
    const int rt = wv & 1, js = wv >> 1;
    const int fr = lane & 15, fq = lane >> 4;

    // ---- stage Kp + qp own rows (coalesced uint loads)
    {
        const unsigned int* srck = (const unsigned int*)kpb;
        const unsigned int* srcq = (const unsigned int*)qpb;
        for (int i = tid; i < 2048; i += 512) {
            int j = i >> 6, mu = i & 63;
            ((unsigned int*)&bufK[j * 136])[mu] = srck[(rowstart + j) * 64 + mu];
            ((unsigned int*)&bufQ[j * 136])[mu] = srcq[(rowstart + j) * 64 + mu];
        }
    }
    // ---- stage S0^T (16 bf16/thread, coalesced 32B)
    {
        const int pm = tid >> 2, peb = (tid & 3) * 16;
        const unsigned short* src = &S0pre[(h * 32 + s) * (M * D) + pm * D + peb];
        short8 s0a = *(const short8*)&src[0];
        short8 s0b = *(const short8*)&src[8];
#pragma unroll
        for (int j = 0; j < 8; j++) {
            s0t[(peb + j) * 136 + pm] = s0a[j];
            s0t[(peb + 8 + j) * 136 + pm] = s0b[j];
        }
    }
    // ---- stage V^T (fp32 -> bf16), own 32 rows
    {
        const int j = tid >> 4, e4 = (tid & 15) * 4;
        float4 gv = *(const float4*)&v[(rowstart + j) * D + e4];
        vT[(e4 + 0) * 40 + j] = (short)f2bf(gv.x);
        vT[(e4 + 1) * 40 + j] = (short)f2bf(gv.y);
        vT[(e4 + 2) * 40 + j] = (short)f2bf(gv.z);
        vT[(e4 + 3) * 40 + j] = (short)f2bf(gv.w);
    }
    float zinit = 0.f;
    if (tid < 128) zinit = zpre[(h * 32 + s) * M + tid];
    __syncthreads(); // (1)

    // ---- z-scan -> W (tid<128, seeded from zpre)
    if (tid < 128) {
        const int m = tid;
        float z = zinit;
#pragma unroll 8
        for (int r = 0; r < 32; r++) {
            z += bf2f((unsigned short)bufK[r * 136 + m]);
            bufW[r * 136 + m] = (short)f2bf(
                bf2f((unsigned short)bufQ[r * 136 + m]) * __builtin_amdgcn_rcpf(z));
        }
    }
    __syncthreads(); // (2) W ready

    // ---- P2a: out = W @ S0 (K=128) — all 8 waves, tile (rt, js)
    f32x4 acc2 = (f32x4){0.f, 0.f, 0.f, 0.f};
#pragma unroll
    for (int kt = 0; kt < 4; kt++) {
        short8 a = *(const short8*)&bufW[(16 * rt + fr) * 136 + kt * 32 + fq * 8];
        short8 bb = *(const short8*)&s0t[(16 * js + fr) * 136 + kt * 32 + fq * 8];
        acc2 = __builtin_amdgcn_mfma_f32_16x16x32_bf16(a, bb, acc2, 0, 0, 0);
    }
    // ---- P1: Pb = tril(W @ Kp^T) — waves 0..3 only, tile (rt, jt)
    if (wv < 4) {
        const int jt = wv >> 1;
        f32x4 acc1 = (f32x4){0.f, 0.f, 0.f, 0.f};
#pragma unroll
        for (int kt = 0; kt < 4; kt++) {
            short8 a = *(const short8*)&bufW[(16 * rt + fr) * 136 + kt * 32 + fq * 8];
            short8 bb = *(const short8*)&bufK[(16 * jt + fr) * 136 + kt * 32 + fq * 8];
            acc1 = __builtin_amdgcn_mfma_f32_16x16x32_bf16(a, bb, acc1, 0, 0, 0);
        }
        const int j = 16 * jt + fr;
#pragma unroll
        for (int reg = 0; reg < 4; reg++) {
            const int nloc = 16 * rt + fq * 4 + reg;
            float val = (j <= nloc) ? acc1[reg] : 0.f;
            bufP[nloc * 40 + j] = (short)f2bf(val);
        }
    }
    __syncthreads(); // (3) Pb ready

    // ---- P2b: out += P @ V (K=32)
    {
        short8 a = *(const short8*)&bufP[(16 * rt + fr) * 40 + fq * 8];
        short8 bb = *(const short8*)&vT[(16 * js + fr) * 40 + fq * 8];
        acc2 = __builtin_amdgcn_mfma_f32_16x16x32_bf16(a, bb, acc2, 0, 0, 0);
    }

    // ---- epilogue
#pragma unroll
    for (int reg = 0; reg < 4; reg++) {
        out[(rowstart + 16 * rt + fq * 4 + reg) * D + 16 * js + fr] = acc2[reg];
    }
}

extern "C" void kernel_launch(void* const* d_in, const int* in_sizes, int n_in,
                              void* d_out, int out_size, void* d_ws, size_t ws_size,
                              hipStream_t stream) {
    const float* q = (const float*)d_in[0];
    const float* k = (const float*)d_in[1];
    const float* v = (const float*)d_in[2];
    const float* proj = (const float*)d_in[3];
    float* out = (float*)d_out;

    // workspace: kpart 128KB fp32; qpb/kpb 2MB bf16 each; Gpb 4MB bf16;
    // zpre 128KB fp32; S0pre 4MB bf16 (s-granular, R15)
    float* ws = (float*)d_ws;
    float* kpart = ws;                                           // H*32*M
    unsigned short* qpb = (unsigned short*)(kpart + H * 32 * M); // H*N*M
    unsigned short* kpb = qpb + H * N * M;                       // H*N*M
    unsigned short* Gpb = kpb + H * N * M;                       // H*32*M*D
    float* zpre = (float*)(Gpb + H * 32 * M * D);                // H*32*M
    unsigned short* S0pre = (unsigned short*)(zpre + H * 32 * M); // H*32*M*D

    k_projg<<<dim3(32, H), 512, 0, stream>>>(q, k, proj, v, qpb, kpb, Gpb,
                                             kpart);
    k_prefix<<<dim3(64), 256, 0, stream>>>(kpart, Gpb, zpre, S0pre);
    k_attn<<<dim3(H * 32), 512, 0, stream>>>(qpb, kpb, zpre, S0pre, v, out);
}